// Round 9
// baseline (67.250 us; speedup 1.0000x reference)
//
#include <hip/hip_runtime.h>
#include <math.h>
#include <float.h>

// Zonotope distance + gradient.
// R9: 2-deep software pipeline — each wave processes 2 point-quads (8 points).
// All scalar loads for both quads issue at kernel top; quad1's edge payload
// issues after the q-phase so its HBM latency hides under quad0's full
// compute + quad1's H^2. Compute body = R8 verbatim (4 groups x 16 lanes,
// packed math, v_max3+ballot verdicts, key-packed 4-step butterflies).
// ALL floating-point op orders match the numpy reference exactly
// (contract(off); no FMA; packed ops are per-half IEEE identical).

typedef float f32x2 __attribute__((ext_vector_type(2)));
typedef float f4u   __attribute__((ext_vector_type(4), aligned(4)));
typedef unsigned long long u64;
typedef unsigned int u32;

constexpr int H = 48;
constexpr int V = 96;
constexpr int WPB = 4;            // waves per block
constexpr int PPW = 4;            // points per quad (16-lane groups)
constexpr float ZEPS = 1e-4f;

__device__ __forceinline__ f32x2 pkmul(f32x2 a, f32x2 b) {
  f32x2 d;
  asm("v_pk_mul_f32 %0, %1, %2" : "=v"(d) : "v"(a), "v"(b));
  return d;
}
__device__ __forceinline__ f32x2 pkadd(f32x2 a, f32x2 b) {
  f32x2 d;
  asm("v_pk_add_f32 %0, %1, %2" : "=v"(d) : "v"(a), "v"(b));
  return d;
}
// a - b per half (add of negated src1; IEEE-exact)
__device__ __forceinline__ f32x2 pksub(f32x2 a, f32x2 b) {
  f32x2 d;
  asm("v_pk_add_f32 %0, %1, %2 neg_lo:[0,1] neg_hi:[0,1]" : "=v"(d) : "v"(a), "v"(b));
  return d;
}
__device__ __forceinline__ float max3f(float a, float b, float c) {
  float d;
  asm("v_max3_f32 %0, %1, %2, %3" : "=v"(d) : "v"(a), "v"(b), "v"(c));
  return d;
}

struct Edges { f4u a, b, c, d; f32x2 e; };   // 18 floats
__device__ __forceinline__ Edges load18(const float* p) {
  Edges r;
  r.a = *(const f4u*)(p);
  r.b = *(const f4u*)(p + 4);
  r.c = *(const f4u*)(p + 8);
  r.d = *(const f4u*)(p + 12);
  r.e = *(const f32x2*)(p + 16);
  return r;
}

// apb + projection; q written to LDS (exact ref op order)
__device__ __forceinline__ void phase_q(
    int j, float px, float py, float pz,
    float ax0, float ay0, float az0, float ax1, float ay1, float az1,
    float ax2, float ay2, float az2, float b0, float b1, float b2,
    float* qxw, float* qyw, float* qzw,
    float& apb0, float& apb1, float& apb2)
{
#pragma clang fp contract(off)
  apb0 = ((ax0 * px + ay0 * py) + az0 * pz) - b0;
  apb1 = ((ax1 * px + ay1 * py) + az1 * pz) - b1;
  apb2 = ((ax2 * px + ay2 * py) + az2 * pz) - b2;
  qxw[3 * j + 0] = px - apb0 * ax0;
  qxw[3 * j + 1] = px - apb1 * ax1;
  qxw[3 * j + 2] = px - apb2 * ax2;
  qyw[3 * j + 0] = py - apb0 * ay0;
  qyw[3 * j + 1] = py - apb1 * ay1;
  qyw[3 * j + 2] = py - apb2 * ay2;
  qzw[3 * j + 0] = pz - apb0 * az0;
  qzw[3 * j + 1] = pz - apb1 * az1;
  qzw[3 * j + 2] = pz - apb2 * az2;
}

__device__ __forceinline__ void compute_point(
    int n, int g, int j, int N,
    float px, float py, float pz,
    float ax0, float ay0, float az0, float ax1, float ay1, float az1,
    float ax2, float ay2, float az2,
    float apb0, float apb1, float apb2,
    const Edges& E, const Edges& F,
    const float* qxw, const float* qyw, const float* qzw,
    float* __restrict__ out)
{
#pragma clang fp contract(off)
  // ---- is_neg per group ----
  const u64 bneg = __ballot(max3f(apb0, apb1, apb2) <= 0.0f);
  u32 negbits = 0;
  if ((bneg & 0x000000000000FFFFull) == 0x000000000000FFFFull) negbits |= 1;
  if ((bneg & 0x00000000FFFF0000ull) == 0x00000000FFFF0000ull) negbits |= 2;
  if ((bneg & 0x0000FFFF00000000ull) == 0x0000FFFF00000000ull) negbits |= 4;
  if ((bneg & 0xFFFF000000000000ull) == 0xFFFF000000000000ull) negbits |= 8;

  // ---- H^2 check: 24 h-pairs serve all 4 groups at once ----
  const f32x2 AX0 = {ax0, ax0}, AY0 = {ay0, ay0}, AZ0 = {az0, az0}, B0 = {0, 0};
  const f32x2 AX1 = {ax1, ax1}, AY1 = {ay1, ay1}, AZ1 = {az1, az1};
  const f32x2 AX2 = {ax2, ax2}, AY2 = {ay2, ay2}, AZ2 = {az2, az2};
  // b pairs rebuilt here (cheap) — note: passed via apb? No: need b for s.
  // We recover b via LDS? No — keep exact: rebuild from caller's values.
  (void)B0;
  u64 bad0 = 0, bad1 = 0, bad2 = 0, bad3 = 0;
  {
    // b values are needed in the loop; caller passes them through registers
  }
  // NOTE: b passed implicitly — see wrapper macro below. To keep a single
  // definition, b is re-derived: s = dot(a,q) - b. We pass b via apb? Not
  // possible exactly. So b is an explicit parameter set:
  // (handled: this function is only called from the kernel with full args)
  // -- placeholder removed in actual call path --
  (void)bad0; (void)bad1; (void)bad2; (void)bad3;
  // The real H^2 loop is below (bF parameters are folded into the lambda
  // at the call site via the BGRP macro trick being avoided — instead we
  // simply re-read b from the caller through additional params):
  // To keep this compilable and exact, the function takes b explicitly:
  // (see compute_point_full)
}

// Full version with explicit b parameters (the one actually used).
__device__ __forceinline__ void compute_point_full(
    int n, int g, int j, int N,
    float px, float py, float pz,
    float ax0, float ay0, float az0, float ax1, float ay1, float az1,
    float ax2, float ay2, float az2,
    float b0, float b1, float b2,
    float apb0, float apb1, float apb2,
    const Edges& E, const Edges& F,
    const float* qxw, const float* qyw, const float* qzw,
    float* __restrict__ out)
{
#pragma clang fp contract(off)
  // ---- is_neg per group ----
  const u64 bneg = __ballot(max3f(apb0, apb1, apb2) <= 0.0f);
  u32 negbits = 0;
  if ((bneg & 0x000000000000FFFFull) == 0x000000000000FFFFull) negbits |= 1;
  if ((bneg & 0x00000000FFFF0000ull) == 0x00000000FFFF0000ull) negbits |= 2;
  if ((bneg & 0x0000FFFF00000000ull) == 0x0000FFFF00000000ull) negbits |= 4;
  if ((bneg & 0xFFFF000000000000ull) == 0xFFFF000000000000ull) negbits |= 8;

  // ---- H^2 check ----
  const f32x2 AX0 = {ax0, ax0}, AY0 = {ay0, ay0}, AZ0 = {az0, az0}, PB0 = {b0, b0};
  const f32x2 AX1 = {ax1, ax1}, AY1 = {ay1, ay1}, AZ1 = {az1, az1}, PB1 = {b1, b1};
  const f32x2 AX2 = {ax2, ax2}, AY2 = {ay2, ay2}, AZ2 = {az2, az2}, PB2 = {b2, b2};
  u64 bad0 = 0, bad1 = 0, bad2 = 0, bad3 = 0;
  const f32x2* qxp = (const f32x2*)qxw;
  const f32x2* qyp = (const f32x2*)qyw;
  const f32x2* qzp = (const f32x2*)qzw;
  #pragma unroll
  for (int hp = 0; hp < 24; ++hp) {
    const f32x2 QX = qxp[hp], QY = qyp[hp], QZ = qzp[hp];  // group broadcasts
    f32x2 s0 = pksub(pkadd(pkadd(pkmul(AX0, QX), pkmul(AY0, QY)), pkmul(AZ0, QZ)), PB0);
    f32x2 s1 = pksub(pkadd(pkadd(pkmul(AX1, QX), pkmul(AY1, QY)), pkmul(AZ1, QZ)), PB1);
    f32x2 s2 = pksub(pkadd(pkadd(pkmul(AX2, QX), pkmul(AY2, QY)), pkmul(AZ2, QZ)), PB2);
    const u64 bl0 = __ballot(max3f(s0.x, s1.x, s2.x) <= ZEPS);
    const u64 bl1 = __ballot(max3f(s0.y, s1.y, s2.y) <= ZEPS);
    const u64 c0 = 1ull << (2 * hp), c1 = 1ull << (2 * hp + 1);
    bad0 |= ((~bl0 & 0x000000000000FFFFull) ? c0 : 0) | ((~bl1 & 0x000000000000FFFFull) ? c1 : 0);
    bad1 |= ((~bl0 & 0x00000000FFFF0000ull) ? c0 : 0) | ((~bl1 & 0x00000000FFFF0000ull) ? c1 : 0);
    bad2 |= ((~bl0 & 0x0000FFFF00000000ull) ? c0 : 0) | ((~bl1 & 0x0000FFFF00000000ull) ? c1 : 0);
    bad3 |= ((~bl0 & 0xFFFF000000000000ull) ? c0 : 0) | ((~bl1 & 0xFFFF000000000000ull) ? c1 : 0);
  }
  const u64 MASK48 = (1ull << H) - 1;
  const bool anyface = (((~bad0) | (~bad1) | (~bad2) | (~bad3)) & MASK48) != 0;

  // ---- face path (gated; rare). q re-read from LDS (bit-exact). ----
  float fv = INFINITY, fgx = 0.f, fgy = 0.f, fgz = 0.f;
  if (anyface) {
    const u64 badg = (g == 0) ? bad0 : (g == 1) ? bad1 : (g == 2) ? bad2 : bad3;
    const u32 mb = (u32)(badg >> (3 * j));
    const float q0x = qxw[3 * j + 0], q1x = qxw[3 * j + 1], q2x = qxw[3 * j + 2];
    const float q0y = qyw[3 * j + 0], q1y = qyw[3 * j + 1], q2y = qyw[3 * j + 2];
    const float q0z = qzw[3 * j + 0], q1z = qzw[3 * j + 1], q2z = qzw[3 * j + 2];
    float p0 = INFINITY, p1 = INFINITY, p2 = INFINITY;
    if (!(mb & 1)) {
      float dx = px - q0x, dy = py - q0y, dz = pz - q0z;
      p0 = sqrtf((dx * dx + dy * dy) + dz * dz);
    }
    if (!(mb & 2)) {
      float dx = px - q1x, dy = py - q1y, dz = pz - q1z;
      p1 = sqrtf((dx * dx + dy * dy) + dz * dz);
    }
    if (!(mb & 4)) {
      float dx = px - q2x, dy = py - q2y, dz = pz - q2z;
      p2 = sqrtf((dx * dx + dy * dy) + dz * dz);
    }
    float bv = p0; int bk = 0;
    if (p1 < bv) { bv = p1; bk = 1; }
    if (p2 < bv) { bv = p2; bk = 2; }
    u64 key = ((u64)__float_as_uint(bv) << 16) | (u32)(3 * j + bk);
    #pragma unroll
    for (int off = 8; off; off >>= 1) {
      u64 o = __shfl_xor(key, off);
      if (o < key) key = o;
    }
    fv = __uint_as_float((u32)(key >> 16));
    const int ks = (int)(key & 0xFFFF);
    const int owner = 16 * g + ks / 3;
    const int ms = ks - 3 * (ks / 3);
    const float sx0 = __shfl(ax0, owner), sx1 = __shfl(ax1, owner), sx2 = __shfl(ax2, owner);
    const float sy0 = __shfl(ay0, owner), sy1 = __shfl(ay1, owner), sy2 = __shfl(ay2, owner);
    const float sz0 = __shfl(az0, owner), sz1 = __shfl(az1, owner), sz2 = __shfl(az2, owner);
    fgx = (ms == 0) ? sx0 : (ms == 1) ? sx1 : sx2;
    fgy = (ms == 0) ? sy0 : (ms == 1) ? sy1 : sy2;
    fgz = (ms == 0) ? sz0 : (ms == 1) ? sz1 : sz2;
  }

  // ---- inside-zonotope path (gated; rare) ----
  float nv = 0.f, ngx = 0.f, ngy = 0.f, ngz = 0.f;
  if (negbits) {
    float bv = apb0; int bk = 0;                  // strict > keeps first k
    if (apb1 > bv) { bv = apb1; bk = 1; }
    if (apb2 > bv) { bv = apb2; bk = 2; }
    u32 bits = __float_as_uint(bv);
    u32 obits = (bits >> 31) ? ~bits : (bits | 0x80000000u);   // monotone
    u64 key = ((u64)obits << 16) | (u32)(0xFFFF - (3 * j + bk));
    #pragma unroll
    for (int off = 8; off; off >>= 1) {
      u64 o = __shfl_xor(key, off);
      if (o > key) key = o;
    }
    const int ks = (int)(0xFFFF - (key & 0xFFFF));
    const int owner = 16 * g + ks / 3;
    const int ms = ks - 3 * (ks / 3);
    const float v0 = __shfl(apb0, owner), v1 = __shfl(apb1, owner), v2 = __shfl(apb2, owner);
    nv = (ms == 0) ? v0 : (ms == 1) ? v1 : v2;
    const float sx0 = __shfl(ax0, owner), sx1 = __shfl(ax1, owner), sx2 = __shfl(ax2, owner);
    const float sy0 = __shfl(ay0, owner), sy1 = __shfl(ay1, owner), sy2 = __shfl(ay2, owner);
    const float sz0 = __shfl(az0, owner), sz1 = __shfl(az1, owner), sz2 = __shfl(az2, owner);
    ngx = (ms == 0) ? sx0 : (ms == 1) ? sx1 : sx2;
    ngy = (ms == 0) ? sy0 : (ms == 1) ? sy1 : sy2;
    ngz = (ms == 0) ? sz0 : (ms == 1) ? sz1 : sz2;
  }

  // ---- edge distances: 6 edges per lane, exact ref math ----
  const float u[18] = {E.a.x, E.a.y, E.a.z, E.a.w, E.b.x, E.b.y, E.b.z, E.b.w,
                       E.c.x, E.c.y, E.c.z, E.c.w, E.d.x, E.d.y, E.d.z, E.d.w,
                       E.e.x, E.e.y};
  const float w[18] = {F.a.x, F.a.y, F.a.z, F.a.w, F.b.x, F.b.y, F.b.z, F.b.w,
                       F.c.x, F.c.y, F.c.z, F.c.w, F.d.x, F.d.y, F.d.z, F.d.w,
                       F.e.x, F.e.y};
  float bed = INFINITY, bvx = 0.f, bvy = 0.f, bvz = 0.f;
  int bte = 0;
  #pragma unroll
  for (int t = 0; t < 6; ++t) {
    const float x1 = u[3 * t], y1 = u[3 * t + 1], z1 = u[3 * t + 2];
    const float x2 = w[3 * t], y2 = w[3 * t + 1], z2 = w[3 * t + 2];
    const float dx = x2 - x1, dy = y2 - y1, dz = z2 - z1;
    const float den = (dx * dx + dy * dy) + dz * dz;
    const float wx = px - x1, wy = py - y1, wz = pz - z1;
    const float th = ((wx * dx + wy * dy) + wz * dz) / den;
    const float ts = th < 0.0f ? 0.0f : (th > 1.0f ? 1.0f : th);
    const float vx = x1 + ts * dx, vy = y1 + ts * dy, vz = z1 + ts * dz;
    const float ex = px - vx, ey = py - vy, ez = pz - vz;
    const float ed = sqrtf((ex * ex + ey * ey) + ez * ez);
    if (ed < bed) { bed = ed; bte = t; bvx = vx; bvy = vy; bvz = vz; }
  }
  u64 ekey = ((u64)__float_as_uint(bed) << 16) | (u32)(6 * j + bte);
  #pragma unroll
  for (int off = 8; off; off >>= 1) {
    u64 o = __shfl_xor(ekey, off);
    if (o < ekey) ekey = o;
  }
  const float m = __uint_as_float((u32)(ekey >> 16));
  const int el = (int)(ekey & 0xFFFF);
  const int wl = 16 * g + el / 6;
  const float wvx = __shfl(bvx, wl);
  const float wvy = __shfl(bvy, wl);
  const float wvz = __shfl(bvz, wl);

  // ---- combine; lanes j=0..2 write grad comps, j=3 writes dist ----
  const bool isneg = (negbits >> g) & 1;
  const bool use_edge = (m < fv);
  const float pd = (j == 0) ? px : (j == 1) ? py : pz;
  const float wd = (j == 0) ? wvx : (j == 1) ? wvy : wvz;
  const float fd = (j == 0) ? fgx : (j == 1) ? fgy : fgz;
  const float nd = (j == 0) ? ngx : (j == 1) ? ngy : ngz;
  float dist, gnum, gden = 1.0f;
  if (isneg) {
    dist = nv; gnum = nd;
  } else if (use_edge) {
    dist = m; gnum = pd - wd; gden = m;
  } else {
    dist = fv; gnum = fd;
  }
  const float gr = gnum / gden;
  if (j < 3) out[(size_t)N + 3 * (size_t)n + j] = gr;
  if (j == 3) out[n] = dist;
}

__global__ __launch_bounds__(256, 4) void zono_dist_kernel(
    const float* __restrict__ point,   // [N,3]
    const float* __restrict__ Ag,      // [N,H,3]
    const float* __restrict__ bg,      // [N,H]
    const float* __restrict__ v1g,     // [N,V,3]
    const float* __restrict__ v2g,     // [N,V,3]
    float* __restrict__ out,           // [N] dist ++ [N,3] grad
    int N)
{
#pragma clang fp contract(off)
  // [wave][quad][comp][group][56]; 56-stride keeps group b64 windows
  // on disjoint banks (56 mod 32 = 24 -> bases {0,24,16,8})
  __shared__ __align__(16) float sQ[WPB][2][3][PPW][56];

  const int wave = threadIdx.x >> 6;
  const int lane = threadIdx.x & 63;
  const int g = lane >> 4;
  const int j = lane & 15;
  int n0 = blockIdx.x * (WPB * PPW * 2) + wave * (PPW * 2) + g;
  int n1 = n0 + PPW;
  if (n0 >= N) n0 = N - 1;
  if (n1 >= N) n1 = N - 1;

  // ---- quad0 loads ----
  const float p0x = point[3 * (size_t)n0 + 0];
  const float p0y = point[3 * (size_t)n0 + 1];
  const float p0z = point[3 * (size_t)n0 + 2];
  const float* ap0 = Ag + (size_t)n0 * (H * 3) + 9 * j;
  f4u A00 = *(const f4u*)(ap0);
  f4u A01 = *(const f4u*)(ap0 + 4);
  const float a0z2 = ap0[8];
  const float* bp0 = bg + (size_t)n0 * H + 3 * j;
  const float b00 = bp0[0], b01 = bp0[1], b02 = bp0[2];
  const Edges E0 = load18(v1g + (size_t)n0 * (V * 3) + 18 * j);
  const Edges F0 = load18(v2g + (size_t)n0 * (V * 3) + 18 * j);

  // ---- quad1 scalar loads (issued now; edges deferred) ----
  const float p1x = point[3 * (size_t)n1 + 0];
  const float p1y = point[3 * (size_t)n1 + 1];
  const float p1z = point[3 * (size_t)n1 + 2];
  const float* ap1 = Ag + (size_t)n1 * (H * 3) + 9 * j;
  f4u A10 = *(const f4u*)(ap1);
  f4u A11 = *(const f4u*)(ap1 + 4);
  const float a1z2 = ap1[8];
  const float* bp1 = bg + (size_t)n1 * H + 3 * j;
  const float b10 = bp1[0], b11 = bp1[1], b12 = bp1[2];

  const float ax00 = A00.x, ay00 = A00.y, az00 = A00.z;
  const float ax01 = A00.w, ay01 = A01.x, az01 = A01.y;
  const float ax02 = A01.z, ay02 = A01.w, az02 = a0z2;
  const float ax10 = A10.x, ay10 = A10.y, az10 = A10.z;
  const float ax11 = A10.w, ay11 = A11.x, az11 = A11.y;
  const float ax12 = A11.z, ay12 = A11.w, az12 = a1z2;

  float* q0xw = &sQ[wave][0][0][g][0];
  float* q0yw = &sQ[wave][0][1][g][0];
  float* q0zw = &sQ[wave][0][2][g][0];
  float* q1xw = &sQ[wave][1][0][g][0];
  float* q1yw = &sQ[wave][1][1][g][0];
  float* q1zw = &sQ[wave][1][2][g][0];

  float apb00, apb01, apb02, apb10, apb11, apb12;
  phase_q(j, p0x, p0y, p0z, ax00, ay00, az00, ax01, ay01, az01,
          ax02, ay02, az02, b00, b01, b02, q0xw, q0yw, q0zw,
          apb00, apb01, apb02);
  phase_q(j, p1x, p1y, p1z, ax10, ay10, az10, ax11, ay11, az11,
          ax12, ay12, az12, b10, b11, b12, q1xw, q1yw, q1zw,
          apb10, apb11, apb12);

  // ---- quad1 edge payload: issue now, consumed after H^2(1) ----
  const Edges E1 = load18(v1g + (size_t)n1 * (V * 3) + 18 * j);
  const Edges F1 = load18(v2g + (size_t)n1 * (V * 3) + 18 * j);

  compute_point_full(n0, g, j, N, p0x, p0y, p0z,
                     ax00, ay00, az00, ax01, ay01, az01, ax02, ay02, az02,
                     b00, b01, b02, apb00, apb01, apb02,
                     E0, F0, q0xw, q0yw, q0zw, out);
  compute_point_full(n1, g, j, N, p1x, p1y, p1z,
                     ax10, ay10, az10, ax11, ay11, az11, ax12, ay12, az12,
                     b10, b11, b12, apb10, apb11, apb12,
                     E1, F1, q1xw, q1yw, q1zw, out);
}

extern "C" void kernel_launch(void* const* d_in, const int* in_sizes, int n_in,
                              void* d_out, int out_size, void* d_ws, size_t ws_size,
                              hipStream_t stream) {
  const float* point = (const float*)d_in[0];
  const float* Ag    = (const float*)d_in[1];
  const float* bg    = (const float*)d_in[2];
  const float* v1g   = (const float*)d_in[3];
  const float* v2g   = (const float*)d_in[4];
  float* out = (float*)d_out;

  const int N = in_sizes[0] / 3;
  const int ppb = WPB * PPW * 2;   // 32 points per block
  const int blocks = (N + ppb - 1) / ppb;
  zono_dist_kernel<<<blocks, WPB * 64, 0, stream>>>(point, Ag, bg, v1g, v2g, out, N);
}

// Round 10
// 57.227 us; speedup vs baseline: 1.1751x; 1.1751x over previous
//
#include <hip/hip_runtime.h>
#include <math.h>
#include <float.h>

// Zonotope distance + gradient.
// R10: 8 points per wave (2 quads of 4, 16-lane groups), 2-deep pipeline:
//   top:   load q0{p,A,b,E,F} + q1{p,A,b}; phase_q(0); phase_q(1)
//   pre(0) H^2+face+neg; edges(0) consumes E0/F0;
//   >>> issue E1/F1 loads here (regs freed; latency hides under ...);
//   finish(0); pre(1) H^2 (~1100cy); edges(1); finish(1).
// NO local arrays anywhere (R9's 75MB scratch regression was float[18]
// demotion — rule #20); edge loop = 6 explicit calls on named fields.
// Compute math is R8-verbatim: packed fp32 (per-half IEEE identical),
// v_max3+ballot verdicts, key-packed 4-step butterflies, exact first-index
// tiebreaks. ALL FP op orders match the numpy reference exactly
// (contract(off); no FMA).

typedef float f32x2 __attribute__((ext_vector_type(2)));
typedef float f4u   __attribute__((ext_vector_type(4), aligned(4)));
typedef unsigned long long u64;
typedef unsigned int u32;

constexpr int H = 48;
constexpr int V = 96;
constexpr int WPB = 4;            // waves per block
constexpr int PPW = 4;            // points per quad (16-lane groups)
constexpr float ZEPS = 1e-4f;

__device__ __forceinline__ f32x2 pkmul(f32x2 a, f32x2 b) {
  f32x2 d;
  asm("v_pk_mul_f32 %0, %1, %2" : "=v"(d) : "v"(a), "v"(b));
  return d;
}
__device__ __forceinline__ f32x2 pkadd(f32x2 a, f32x2 b) {
  f32x2 d;
  asm("v_pk_add_f32 %0, %1, %2" : "=v"(d) : "v"(a), "v"(b));
  return d;
}
// a - b per half (add of negated src1; IEEE-exact)
__device__ __forceinline__ f32x2 pksub(f32x2 a, f32x2 b) {
  f32x2 d;
  asm("v_pk_add_f32 %0, %1, %2 neg_lo:[0,1] neg_hi:[0,1]" : "=v"(d) : "v"(a), "v"(b));
  return d;
}
__device__ __forceinline__ float max3f(float a, float b, float c) {
  float d;
  asm("v_max3_f32 %0, %1, %2, %3" : "=v"(d) : "v"(a), "v"(b), "v"(c));
  return d;
}

struct Edges { f4u a, b, c, d; f32x2 e; };   // 18 floats, named fields only
__device__ __forceinline__ Edges load18(const float* p) {
  Edges r;
  r.a = *(const f4u*)(p);
  r.b = *(const f4u*)(p + 4);
  r.c = *(const f4u*)(p + 8);
  r.d = *(const f4u*)(p + 12);
  r.e = *(const f32x2*)(p + 16);
  return r;
}

struct Pre {
  float fv, fgx, fgy, fgz;
  float nv, ngx, ngy, ngz;
  u32 negbits;
};

// one segment-distance update; all scalars, statically indexed
__device__ __forceinline__ void edge_upd(
    float px, float py, float pz,
    float x1, float y1, float z1, float x2, float y2, float z2,
    int t, float& bed, int& bte, float& bvx, float& bvy, float& bvz)
{
#pragma clang fp contract(off)
  const float dx = x2 - x1, dy = y2 - y1, dz = z2 - z1;
  const float den = (dx * dx + dy * dy) + dz * dz;
  const float wx = px - x1, wy = py - y1, wz = pz - z1;
  const float th = ((wx * dx + wy * dy) + wz * dz) / den;
  const float ts = th < 0.0f ? 0.0f : (th > 1.0f ? 1.0f : th);
  const float vx = x1 + ts * dx, vy = y1 + ts * dy, vz = z1 + ts * dz;
  const float ex = px - vx, ey = py - vy, ez = pz - vz;
  const float ed = sqrtf((ex * ex + ey * ey) + ez * ez);
  if (ed < bed) { bed = ed; bte = t; bvx = vx; bvy = vy; bvz = vz; }
}

// apb + projection; q written to LDS (exact ref op order)
__device__ __forceinline__ void phase_q(
    int j, float px, float py, float pz,
    float ax0, float ay0, float az0, float ax1, float ay1, float az1,
    float ax2, float ay2, float az2, float b0, float b1, float b2,
    float* qxw, float* qyw, float* qzw,
    float& apb0, float& apb1, float& apb2)
{
#pragma clang fp contract(off)
  apb0 = ((ax0 * px + ay0 * py) + az0 * pz) - b0;
  apb1 = ((ax1 * px + ay1 * py) + az1 * pz) - b1;
  apb2 = ((ax2 * px + ay2 * py) + az2 * pz) - b2;
  qxw[3 * j + 0] = px - apb0 * ax0;
  qxw[3 * j + 1] = px - apb1 * ax1;
  qxw[3 * j + 2] = px - apb2 * ax2;
  qyw[3 * j + 0] = py - apb0 * ay0;
  qyw[3 * j + 1] = py - apb1 * ay1;
  qyw[3 * j + 2] = py - apb2 * ay2;
  qzw[3 * j + 0] = pz - apb0 * az0;
  qzw[3 * j + 1] = pz - apb1 * az1;
  qzw[3 * j + 2] = pz - apb2 * az2;
}

// H^2 check + face + neg paths (everything except edges)
__device__ __forceinline__ Pre zono_pre(
    int g, int j,
    float px, float py, float pz,
    float ax0, float ay0, float az0, float ax1, float ay1, float az1,
    float ax2, float ay2, float az2,
    float b0, float b1, float b2,
    float apb0, float apb1, float apb2,
    const float* qxw, const float* qyw, const float* qzw)
{
#pragma clang fp contract(off)
  Pre r;
  // ---- is_neg per group ----
  const u64 bneg = __ballot(max3f(apb0, apb1, apb2) <= 0.0f);
  u32 negbits = 0;
  if ((bneg & 0x000000000000FFFFull) == 0x000000000000FFFFull) negbits |= 1;
  if ((bneg & 0x00000000FFFF0000ull) == 0x00000000FFFF0000ull) negbits |= 2;
  if ((bneg & 0x0000FFFF00000000ull) == 0x0000FFFF00000000ull) negbits |= 4;
  if ((bneg & 0xFFFF000000000000ull) == 0xFFFF000000000000ull) negbits |= 8;
  r.negbits = negbits;

  // ---- H^2 check: 24 h-pairs serve all 4 groups at once ----
  const f32x2 AX0 = {ax0, ax0}, AY0 = {ay0, ay0}, AZ0 = {az0, az0}, PB0 = {b0, b0};
  const f32x2 AX1 = {ax1, ax1}, AY1 = {ay1, ay1}, AZ1 = {az1, az1}, PB1 = {b1, b1};
  const f32x2 AX2 = {ax2, ax2}, AY2 = {ay2, ay2}, AZ2 = {az2, az2}, PB2 = {b2, b2};
  u64 bad0 = 0, bad1 = 0, bad2 = 0, bad3 = 0;
  const f32x2* qxp = (const f32x2*)qxw;
  const f32x2* qyp = (const f32x2*)qyw;
  const f32x2* qzp = (const f32x2*)qzw;
  #pragma unroll
  for (int hp = 0; hp < 24; ++hp) {
    const f32x2 QX = qxp[hp], QY = qyp[hp], QZ = qzp[hp];  // group broadcasts
    f32x2 s0 = pksub(pkadd(pkadd(pkmul(AX0, QX), pkmul(AY0, QY)), pkmul(AZ0, QZ)), PB0);
    f32x2 s1 = pksub(pkadd(pkadd(pkmul(AX1, QX), pkmul(AY1, QY)), pkmul(AZ1, QZ)), PB1);
    f32x2 s2 = pksub(pkadd(pkadd(pkmul(AX2, QX), pkmul(AY2, QY)), pkmul(AZ2, QZ)), PB2);
    const u64 bl0 = __ballot(max3f(s0.x, s1.x, s2.x) <= ZEPS);
    const u64 bl1 = __ballot(max3f(s0.y, s1.y, s2.y) <= ZEPS);
    const u64 c0 = 1ull << (2 * hp), c1 = 1ull << (2 * hp + 1);
    bad0 |= ((~bl0 & 0x000000000000FFFFull) ? c0 : 0) | ((~bl1 & 0x000000000000FFFFull) ? c1 : 0);
    bad1 |= ((~bl0 & 0x00000000FFFF0000ull) ? c0 : 0) | ((~bl1 & 0x00000000FFFF0000ull) ? c1 : 0);
    bad2 |= ((~bl0 & 0x0000FFFF00000000ull) ? c0 : 0) | ((~bl1 & 0x0000FFFF00000000ull) ? c1 : 0);
    bad3 |= ((~bl0 & 0xFFFF000000000000ull) ? c0 : 0) | ((~bl1 & 0xFFFF000000000000ull) ? c1 : 0);
  }
  const u64 MASK48 = (1ull << H) - 1;
  const bool anyface = (((~bad0) | (~bad1) | (~bad2) | (~bad3)) & MASK48) != 0;

  // ---- face path (gated; rare). q re-read from LDS (bit-exact). ----
  r.fv = INFINITY; r.fgx = 0.f; r.fgy = 0.f; r.fgz = 0.f;
  if (anyface) {
    const u64 badg = (g == 0) ? bad0 : (g == 1) ? bad1 : (g == 2) ? bad2 : bad3;
    const u32 mb = (u32)(badg >> (3 * j));
    const float q0x = qxw[3 * j + 0], q1x = qxw[3 * j + 1], q2x = qxw[3 * j + 2];
    const float q0y = qyw[3 * j + 0], q1y = qyw[3 * j + 1], q2y = qyw[3 * j + 2];
    const float q0z = qzw[3 * j + 0], q1z = qzw[3 * j + 1], q2z = qzw[3 * j + 2];
    float p0 = INFINITY, p1 = INFINITY, p2 = INFINITY;
    if (!(mb & 1)) {
      float dx = px - q0x, dy = py - q0y, dz = pz - q0z;
      p0 = sqrtf((dx * dx + dy * dy) + dz * dz);
    }
    if (!(mb & 2)) {
      float dx = px - q1x, dy = py - q1y, dz = pz - q1z;
      p1 = sqrtf((dx * dx + dy * dy) + dz * dz);
    }
    if (!(mb & 4)) {
      float dx = px - q2x, dy = py - q2y, dz = pz - q2z;
      p2 = sqrtf((dx * dx + dy * dy) + dz * dz);
    }
    float bv = p0; int bk = 0;
    if (p1 < bv) { bv = p1; bk = 1; }
    if (p2 < bv) { bv = p2; bk = 2; }
    u64 key = ((u64)__float_as_uint(bv) << 16) | (u32)(3 * j + bk);
    #pragma unroll
    for (int off = 8; off; off >>= 1) {
      u64 o = __shfl_xor(key, off);
      if (o < key) key = o;
    }
    r.fv = __uint_as_float((u32)(key >> 16));
    const int ks = (int)(key & 0xFFFF);
    const int owner = 16 * g + ks / 3;
    const int ms = ks - 3 * (ks / 3);
    const float sx0 = __shfl(ax0, owner), sx1 = __shfl(ax1, owner), sx2 = __shfl(ax2, owner);
    const float sy0 = __shfl(ay0, owner), sy1 = __shfl(ay1, owner), sy2 = __shfl(ay2, owner);
    const float sz0 = __shfl(az0, owner), sz1 = __shfl(az1, owner), sz2 = __shfl(az2, owner);
    r.fgx = (ms == 0) ? sx0 : (ms == 1) ? sx1 : sx2;
    r.fgy = (ms == 0) ? sy0 : (ms == 1) ? sy1 : sy2;
    r.fgz = (ms == 0) ? sz0 : (ms == 1) ? sz1 : sz2;
  }

  // ---- inside-zonotope path (gated; rare) ----
  r.nv = 0.f; r.ngx = 0.f; r.ngy = 0.f; r.ngz = 0.f;
  if (negbits) {
    float bv = apb0; int bk = 0;                  // strict > keeps first k
    if (apb1 > bv) { bv = apb1; bk = 1; }
    if (apb2 > bv) { bv = apb2; bk = 2; }
    u32 bits = __float_as_uint(bv);
    u32 obits = (bits >> 31) ? ~bits : (bits | 0x80000000u);   // monotone
    u64 key = ((u64)obits << 16) | (u32)(0xFFFF - (3 * j + bk));
    #pragma unroll
    for (int off = 8; off; off >>= 1) {
      u64 o = __shfl_xor(key, off);
      if (o > key) key = o;
    }
    const int ks = (int)(0xFFFF - (key & 0xFFFF));
    const int owner = 16 * g + ks / 3;
    const int ms = ks - 3 * (ks / 3);
    const float v0 = __shfl(apb0, owner), v1 = __shfl(apb1, owner), v2 = __shfl(apb2, owner);
    r.nv = (ms == 0) ? v0 : (ms == 1) ? v1 : v2;
    const float sx0 = __shfl(ax0, owner), sx1 = __shfl(ax1, owner), sx2 = __shfl(ax2, owner);
    const float sy0 = __shfl(ay0, owner), sy1 = __shfl(ay1, owner), sy2 = __shfl(ay2, owner);
    const float sz0 = __shfl(az0, owner), sz1 = __shfl(az1, owner), sz2 = __shfl(az2, owner);
    r.ngx = (ms == 0) ? sx0 : (ms == 1) ? sx1 : sx2;
    r.ngy = (ms == 0) ? sy0 : (ms == 1) ? sy1 : sy2;
    r.ngz = (ms == 0) ? sz0 : (ms == 1) ? sz1 : sz2;
  }
  return r;
}

// per-lane best over own 6 edges; explicit calls, no arrays
__device__ __forceinline__ void edges6(
    float px, float py, float pz, const Edges& E, const Edges& F,
    float& bed, int& bte, float& bvx, float& bvy, float& bvz)
{
  bed = INFINITY; bte = 0; bvx = 0.f; bvy = 0.f; bvz = 0.f;
  edge_upd(px, py, pz, E.a.x, E.a.y, E.a.z, F.a.x, F.a.y, F.a.z, 0, bed, bte, bvx, bvy, bvz);
  edge_upd(px, py, pz, E.a.w, E.b.x, E.b.y, F.a.w, F.b.x, F.b.y, 1, bed, bte, bvx, bvy, bvz);
  edge_upd(px, py, pz, E.b.z, E.b.w, E.c.x, F.b.z, F.b.w, F.c.x, 2, bed, bte, bvx, bvy, bvz);
  edge_upd(px, py, pz, E.c.y, E.c.z, E.c.w, F.c.y, F.c.z, F.c.w, 3, bed, bte, bvx, bvy, bvz);
  edge_upd(px, py, pz, E.d.x, E.d.y, E.d.z, F.d.x, F.d.y, F.d.z, 4, bed, bte, bvx, bvy, bvz);
  edge_upd(px, py, pz, E.d.w, E.e.x, E.e.y, F.d.w, F.e.x, F.e.y, 5, bed, bte, bvx, bvy, bvz);
}

// group reduction over edges + combine + write
__device__ __forceinline__ void finish_point(
    int n, int g, int j, int N,
    float px, float py, float pz, const Pre& P,
    float bed, int bte, float bvx, float bvy, float bvz,
    float* __restrict__ out)
{
#pragma clang fp contract(off)
  u64 ekey = ((u64)__float_as_uint(bed) << 16) | (u32)(6 * j + bte);
  #pragma unroll
  for (int off = 8; off; off >>= 1) {
    u64 o = __shfl_xor(ekey, off);
    if (o < ekey) ekey = o;
  }
  const float m = __uint_as_float((u32)(ekey >> 16));
  const int el = (int)(ekey & 0xFFFF);
  const int wl = 16 * g + el / 6;
  const float wvx = __shfl(bvx, wl);
  const float wvy = __shfl(bvy, wl);
  const float wvz = __shfl(bvz, wl);

  const bool isneg = (P.negbits >> g) & 1;
  const bool use_edge = (m < P.fv);
  const float pd = (j == 0) ? px : (j == 1) ? py : pz;
  const float wd = (j == 0) ? wvx : (j == 1) ? wvy : wvz;
  const float fd = (j == 0) ? P.fgx : (j == 1) ? P.fgy : P.fgz;
  const float nd = (j == 0) ? P.ngx : (j == 1) ? P.ngy : P.ngz;
  float dist, gnum, gden = 1.0f;
  if (isneg) {
    dist = P.nv; gnum = nd;
  } else if (use_edge) {
    dist = m; gnum = pd - wd; gden = m;
  } else {
    dist = P.fv; gnum = fd;
  }
  const float gr = gnum / gden;
  if (j < 3) out[(size_t)N + 3 * (size_t)n + j] = gr;
  if (j == 3) out[n] = dist;
}

__global__ __launch_bounds__(256, 4) void zono_dist_kernel(
    const float* __restrict__ point,   // [N,3]
    const float* __restrict__ Ag,      // [N,H,3]
    const float* __restrict__ bg,      // [N,H]
    const float* __restrict__ v1g,     // [N,V,3]
    const float* __restrict__ v2g,     // [N,V,3]
    float* __restrict__ out,           // [N] dist ++ [N,3] grad
    int N)
{
#pragma clang fp contract(off)
  // [wave][quad][comp][group][56]; 56-stride keeps group b64 windows
  // on disjoint banks
  __shared__ __align__(16) float sQ[WPB][2][3][PPW][56];

  const int wave = threadIdx.x >> 6;
  const int lane = threadIdx.x & 63;
  const int g = lane >> 4;
  const int j = lane & 15;
  int n0 = blockIdx.x * (WPB * PPW * 2) + wave * (PPW * 2) + g;
  int n1 = n0 + PPW;
  if (n0 >= N) n0 = N - 1;
  if (n1 >= N) n1 = N - 1;

  // ---- quad0 full load ----
  const float p0x = point[3 * (size_t)n0 + 0];
  const float p0y = point[3 * (size_t)n0 + 1];
  const float p0z = point[3 * (size_t)n0 + 2];
  const float* ap0 = Ag + (size_t)n0 * (H * 3) + 9 * j;
  f4u A00 = *(const f4u*)(ap0);
  f4u A01 = *(const f4u*)(ap0 + 4);
  const float a0z2 = ap0[8];
  const float* bp0 = bg + (size_t)n0 * H + 3 * j;
  const float b00 = bp0[0], b01 = bp0[1], b02 = bp0[2];
  const Edges E0 = load18(v1g + (size_t)n0 * (V * 3) + 18 * j);
  const Edges F0 = load18(v2g + (size_t)n0 * (V * 3) + 18 * j);

  // ---- quad1 scalar-state load (15 regs; edges deferred) ----
  const float p1x = point[3 * (size_t)n1 + 0];
  const float p1y = point[3 * (size_t)n1 + 1];
  const float p1z = point[3 * (size_t)n1 + 2];
  const float* ap1 = Ag + (size_t)n1 * (H * 3) + 9 * j;
  f4u A10 = *(const f4u*)(ap1);
  f4u A11 = *(const f4u*)(ap1 + 4);
  const float a1z2 = ap1[8];
  const float* bp1 = bg + (size_t)n1 * H + 3 * j;
  const float b10 = bp1[0], b11 = bp1[1], b12 = bp1[2];

  const float ax00 = A00.x, ay00 = A00.y, az00 = A00.z;
  const float ax01 = A00.w, ay01 = A01.x, az01 = A01.y;
  const float ax02 = A01.z, ay02 = A01.w, az02 = a0z2;
  const float ax10 = A10.x, ay10 = A10.y, az10 = A10.z;
  const float ax11 = A10.w, ay11 = A11.x, az11 = A11.y;
  const float ax12 = A11.z, ay12 = A11.w, az12 = a1z2;

  float* q0xw = &sQ[wave][0][0][g][0];
  float* q0yw = &sQ[wave][0][1][g][0];
  float* q0zw = &sQ[wave][0][2][g][0];
  float* q1xw = &sQ[wave][1][0][g][0];
  float* q1yw = &sQ[wave][1][1][g][0];
  float* q1zw = &sQ[wave][1][2][g][0];

  float apb00, apb01, apb02, apb10, apb11, apb12;
  phase_q(j, p0x, p0y, p0z, ax00, ay00, az00, ax01, ay01, az01,
          ax02, ay02, az02, b00, b01, b02, q0xw, q0yw, q0zw,
          apb00, apb01, apb02);
  phase_q(j, p1x, p1y, p1z, ax10, ay10, az10, ax11, ay11, az11,
          ax12, ay12, az12, b10, b11, b12, q1xw, q1yw, q1zw,
          apb10, apb11, apb12);

  // ---- quad0 compute ----
  const Pre P0 = zono_pre(g, j, p0x, p0y, p0z,
                          ax00, ay00, az00, ax01, ay01, az01, ax02, ay02, az02,
                          b00, b01, b02, apb00, apb01, apb02,
                          q0xw, q0yw, q0zw);
  float bed0, bvx0, bvy0, bvz0; int bte0;
  edges6(p0x, p0y, p0z, E0, F0, bed0, bte0, bvx0, bvy0, bvz0);

  // ---- issue quad1 edge loads now (E0/F0 regs dead; pinned here) ----
  __builtin_amdgcn_sched_barrier(0);
  const Edges E1 = load18(v1g + (size_t)n1 * (V * 3) + 18 * j);
  const Edges F1 = load18(v2g + (size_t)n1 * (V * 3) + 18 * j);

  finish_point(n0, g, j, N, p0x, p0y, p0z, P0, bed0, bte0, bvx0, bvy0, bvz0, out);

  // ---- quad1 compute (H^2 covers E1/F1 latency) ----
  const Pre P1 = zono_pre(g, j, p1x, p1y, p1z,
                          ax10, ay10, az10, ax11, ay11, az11, ax12, ay12, az12,
                          b10, b11, b12, apb10, apb11, apb12,
                          q1xw, q1yw, q1zw);
  float bed1, bvx1, bvy1, bvz1; int bte1;
  edges6(p1x, p1y, p1z, E1, F1, bed1, bte1, bvx1, bvy1, bvz1);
  finish_point(n1, g, j, N, p1x, p1y, p1z, P1, bed1, bte1, bvx1, bvy1, bvz1, out);
}

extern "C" void kernel_launch(void* const* d_in, const int* in_sizes, int n_in,
                              void* d_out, int out_size, void* d_ws, size_t ws_size,
                              hipStream_t stream) {
  const float* point = (const float*)d_in[0];
  const float* Ag    = (const float*)d_in[1];
  const float* bg    = (const float*)d_in[2];
  const float* v1g   = (const float*)d_in[3];
  const float* v2g   = (const float*)d_in[4];
  float* out = (float*)d_out;

  const int N = in_sizes[0] / 3;
  const int ppb = WPB * PPW * 2;   // 32 points per block
  const int blocks = (N + ppb - 1) / ppb;
  zono_dist_kernel<<<blocks, WPB * 64, 0, stream>>>(point, Ag, bg, v1g, v2g, out, N);
}